// Round 6
// baseline (304.451 us; speedup 1.0000x reference)
//
#include <hip/hip_runtime.h>
#include <math.h>

#define T_LEN   2048
#define NKH     16
#define NVH     32
#define HD      64
#define KEY_DIM 1024
#define VAL_DIM 2048
#define CONV_DIM 4096
#define NCHUNK  32
#define CL      64

typedef float fl4 __attribute__((ext_vector_type(4)));

__device__ __forceinline__ float sigmoid_f(float x) { return 1.f / (1.f + __expf(-x)); }
__device__ __forceinline__ float rdlane(float v, int i) {
    return __int_as_float(__builtin_amdgcn_readlane(__float_as_int(v), i));
}

// ---------------------------------------------------------------------------
// Kernel 1: causal conv1d (W=4) + silu + head split + qk l2norm + gates.
// v output is pre-scaled by beta (the only consumer of v is beta*v).
// ---------------------------------------------------------------------------
__global__ __launch_bounds__(256) void prep_kernel(
    const float* __restrict__ x,        // [T, 4096]
    const float* __restrict__ cs,       // [3, 4096]
    const float* __restrict__ w,        // [4096, 4]
    const float* __restrict__ bsrc,     // [T, 32]
    const float* __restrict__ a,        // [T, 32]
    const float* __restrict__ A_log,    // [32]
    const float* __restrict__ dt_bias,  // [32]
    float* __restrict__ qn,             // [T, 16, 64]
    float* __restrict__ kn,             // [T, 16, 64]
    float* __restrict__ vb,             // [T, 32, 64]  beta*v
    float* __restrict__ g,              // [T, 32]
    float* __restrict__ beta)           // [T, 32]
{
    const int t   = blockIdx.x;
    const int tid = threadIdx.x;
    const int d0  = tid * 16;

    fl4 r4[4];
    #pragma unroll
    for (int grp = 0; grp < 4; ++grp) {
        const int d = d0 + grp * 4;
        fl4 xv[4], wq[4];
        #pragma unroll
        for (int wi = 0; wi < 4; ++wi) {
            const int row = t - 3 + wi;
            const float* src = (row >= 0) ? (x + (size_t)row * CONV_DIM + d)
                                          : (cs + (size_t)(row + 3) * CONV_DIM + d);
            xv[wi] = *(const fl4*)src;
        }
        #pragma unroll
        for (int j = 0; j < 4; ++j) wq[j] = *(const fl4*)(w + (size_t)(d + j) * 4);
        #pragma unroll
        for (int j = 0; j < 4; ++j) {
            float acc = xv[0][j] * wq[j][0];
            acc = fmaf(xv[1][j], wq[j][1], acc);
            acc = fmaf(xv[2][j], wq[j][2], acc);
            acc = fmaf(xv[3][j], wq[j][3], acc);
            r4[grp][j] = acc * sigmoid_f(acc);
        }
    }

    if (tid < 128) {
        float ss = 0.f;
        #pragma unroll
        for (int grp = 0; grp < 4; ++grp)
            #pragma unroll
            for (int j = 0; j < 4; ++j) ss = fmaf(r4[grp][j], r4[grp][j], ss);
        ss += __shfl_xor(ss, 1);
        ss += __shfl_xor(ss, 2);
        const bool is_q = (tid < 64);
        float scale = (is_q ? 0.125f : 1.0f) / sqrtf(ss + 1e-6f);
        float* dst = is_q ? (qn + (size_t)t * KEY_DIM + d0)
                          : (kn + (size_t)t * KEY_DIM + (d0 - KEY_DIM));
        #pragma unroll
        for (int grp = 0; grp < 4; ++grp) {
            fl4 o;
            #pragma unroll
            for (int j = 0; j < 4; ++j) o[j] = r4[grp][j] * scale;
            *(fl4*)(dst + grp * 4) = o;
        }
    } else {
        const int hh = (d0 - 2 * KEY_DIM) >> 6;
        const float bb = sigmoid_f(bsrc[(size_t)t * NVH + hh]);
        float* dst = vb + (size_t)t * VAL_DIM + (d0 - 2 * KEY_DIM);
        #pragma unroll
        for (int grp = 0; grp < 4; ++grp) {
            fl4 o;
            #pragma unroll
            for (int j = 0; j < 4; ++j) o[j] = r4[grp][j] * bb;
            *(fl4*)(dst + grp * 4) = o;
        }
    }

    if (tid < 32) {
        float av = a[(size_t)t * NVH + tid] + dt_bias[tid];
        float sp = fmaxf(av, 0.f) + log1pf(__expf(-fabsf(av)));
        g[(size_t)t * NVH + tid]    = -__expf(A_log[tid]) * sp;
        beta[(size_t)t * NVH + tid] = sigmoid_f(bsrc[(size_t)t * NVH + tid]);
    }
}

// ---------------------------------------------------------------------------
// Kernel 2 (phase 1): per (chunk c, v-head h), fully parallel.
// MT/SU epilogues now use wave-uniform fl4 broadcasts of Tm rows (4 b128
// per step instead of 64 scalar b32) — ~1900 fewer instrs/thread.
// ---------------------------------------------------------------------------
__global__ __launch_bounds__(256) void phase1_kernel(
    const float* __restrict__ qn, const float* __restrict__ kn,
    const float* __restrict__ gws, const float* __restrict__ bws,
    float* __restrict__ gam_g, float* __restrict__ bg_g,
    float* __restrict__ KT_g, float* __restrict__ QT_g,
    float* __restrict__ MTt_g, float* __restrict__ SUt_g)
{
    const int bid = blockIdx.x;
    const int c = bid >> 5, h = bid & 31, kh = h >> 1;
    const int tid = threadIdx.x, lane = tid & 63, wv = tid >> 6;

    __shared__ float Ks[64][68], Qs[64][68], Am[64][68], Tm[64][68];
    __shared__ float Gs[64], Dend[64], Bet[64];
    __shared__ float Xs[4][16][17];

    #pragma unroll
    for (int p = 0; p < 4; ++p) {
        int idx = p * 256 + tid;
        int t = idx >> 4, i4 = (idx & 15) * 4;
        *(fl4*)&Ks[t][i4] = *(const fl4*)&kn[(size_t)(c*64+t)*KEY_DIM + kh*64 + i4];
        *(fl4*)&Qs[t][i4] = *(const fl4*)&qn[(size_t)(c*64+t)*KEY_DIM + kh*64 + i4];
    }
    for (int idx = tid; idx < 64*64; idx += 256) {
        int t = idx >> 6, s = idx & 63;
        Tm[t][s] = (t == s) ? 1.f : 0.f;
    }
    if (tid < 64) {
        float gv = gws[(size_t)(c*64+lane)*NVH + h];
        #pragma unroll
        for (int d = 1; d < 64; d <<= 1) {
            float nv = __shfl_up(gv, d);
            if (lane >= d) gv += nv;
        }
        Gs[lane] = gv;
        float g63 = __shfl(gv, 63);
        Dend[lane] = __expf(g63 - gv);
        float bb = bws[(size_t)(c*64+lane)*NVH + h];
        Bet[lane] = bb;
        float ga = __expf(gv);
        gam_g[(size_t)(c*NVH+h)*64 + lane] = ga;
        bg_g[(size_t)(c*NVH+h)*64 + lane]  = ga * bb;
    }
    __syncthreads();

    if ((h & 1) == 0) {
        float* kdst = KT_g + (size_t)(c*NKH + kh)*64*64;
        float* qdst = QT_g + (size_t)(c*NKH + kh)*64*64;
        const int t = lane;
        #pragma unroll
        for (int ii = 0; ii < 16; ++ii) {
            int i = wv*16 + ii;
            kdst[i*64 + t] = Ks[t][i];
            qdst[i*64 + t] = Qs[t][i];
        }
    }

    float accK[16], accQ[16];
    {
        #pragma unroll
        for (int j = 0; j < 16; ++j) { accK[j] = 0.f; accQ[j] = 0.f; }
        const int t = lane, sbase = wv * 16;
        for (int i4 = 0; i4 < 64; i4 += 4) {
            fl4 kt = *(const fl4*)&Ks[t][i4];
            fl4 qt = *(const fl4*)&Qs[t][i4];
            #pragma unroll
            for (int sj = 0; sj < 16; ++sj) {
                fl4 ks = *(const fl4*)&Ks[sbase + sj][i4];
                accK[sj] += kt[0]*ks[0] + kt[1]*ks[1] + kt[2]*ks[2] + kt[3]*ks[3];
                accQ[sj] += qt[0]*ks[0] + qt[1]*ks[1] + qt[2]*ks[2] + qt[3]*ks[3];
            }
        }
    }
    __syncthreads();
    {
        const int t = lane, sbase = wv * 16;
        const float gt = Gs[t], bt = Bet[t];
        #pragma unroll
        for (int sj = 0; sj < 16; ++sj) {
            int s = sbase + sj;
            float e = __expf(gt - Gs[s]);
            Am[t][s] = (s < t)  ? bt * e * accK[sj] : 0.f;
            Qs[t][s] = (s <= t) ? e * accQ[sj] : 0.f;   // M in-place
        }
    }
    __syncthreads();

    // T = (I+A)^{-1}: diagonal 16x16 blocks by forward substitution
    if (lane < 16) {
        const int base = wv * 16;
        const int sj = lane, s = base + sj;
        for (int tl = 1; tl < 16; ++tl) {
            int t = base + tl;
            if (sj < tl) {
                float acc = 0.f;
                for (int il = sj; il < tl; ++il)
                    acc += Am[t][base + il] * Tm[base + il][s];
                Tm[t][s] = -acc;
            }
        }
    }
    for (int L = 1; L <= 3; ++L) {
        __syncthreads();
        if (wv < 4 - L) {
            const int J = wv, I = wv + L;
            const int r = lane & 15, cg = lane >> 4;
            float X[4] = {0.f,0.f,0.f,0.f};
            for (int Kb = J; Kb < I; ++Kb) {
                #pragma unroll
                for (int p = 0; p < 16; ++p) {
                    float av = Am[I*16 + r][Kb*16 + p];
                    #pragma unroll
                    for (int mm = 0; mm < 4; ++mm)
                        X[mm] += av * Tm[Kb*16 + p][J*16 + cg + 4*mm];
                }
            }
            #pragma unroll
            for (int mm = 0; mm < 4; ++mm) Xs[wv][r][cg + 4*mm] = X[mm];
            float Y[4] = {0.f,0.f,0.f,0.f};
            #pragma unroll
            for (int p = 0; p < 16; ++p) {
                float td = Tm[I*16 + r][I*16 + p];
                #pragma unroll
                for (int mm = 0; mm < 4; ++mm)
                    Y[mm] += td * Xs[wv][p][cg + 4*mm];
            }
            #pragma unroll
            for (int mm = 0; mm < 4; ++mm)
                Tm[I*16 + r][J*16 + cg + 4*mm] = -Y[mm];
        }
    }
    __syncthreads();

    // MTt[s][t] = (M * T)[t][s]; M lives in Qs.  Uniform fl4 Tm reads.
    {
        float acc[16];
        #pragma unroll
        for (int j = 0; j < 16; ++j) acc[j] = 0.f;
        const int t = lane, sbase = wv * 16;
        for (int i = 0; i < 64; i += 4) {
            fl4 mv4 = *(const fl4*)&Qs[t][i];
            #pragma unroll
            for (int r = 0; r < 4; ++r) {
                fl4 ta = *(const fl4*)&Tm[i+r][sbase + 0];
                fl4 tb = *(const fl4*)&Tm[i+r][sbase + 4];
                fl4 tc = *(const fl4*)&Tm[i+r][sbase + 8];
                fl4 td = *(const fl4*)&Tm[i+r][sbase + 12];
                #pragma unroll
                for (int q = 0; q < 4; ++q) {
                    acc[q]      = fmaf(mv4[r], ta[q], acc[q]);
                    acc[4 + q]  = fmaf(mv4[r], tb[q], acc[4 + q]);
                    acc[8 + q]  = fmaf(mv4[r], tc[q], acc[8 + q]);
                    acc[12 + q] = fmaf(mv4[r], td[q], acc[12 + q]);
                }
            }
        }
        float* dst = MTt_g + (size_t)(c*NVH + h)*64*64;
        #pragma unroll
        for (int sj = 0; sj < 16; ++sj)
            dst[(sbase + sj)*64 + t] = acc[sj];
    }
    // SUt[s][d] = sum_t Dend[t]*K[t][d]*Tm[t][s].  Uniform fl4 Tm reads.
    {
        float acc[16];
        #pragma unroll
        for (int j = 0; j < 16; ++j) acc[j] = 0.f;
        const int d = lane, sbase = wv * 16;
        for (int t = 0; t < 64; ++t) {
            float kd = Ks[t][d] * Dend[t];
            fl4 ta = *(const fl4*)&Tm[t][sbase + 0];
            fl4 tb = *(const fl4*)&Tm[t][sbase + 4];
            fl4 tc = *(const fl4*)&Tm[t][sbase + 8];
            fl4 td = *(const fl4*)&Tm[t][sbase + 12];
            #pragma unroll
            for (int q = 0; q < 4; ++q) {
                acc[q]      = fmaf(kd, ta[q], acc[q]);
                acc[4 + q]  = fmaf(kd, tb[q], acc[4 + q]);
                acc[8 + q]  = fmaf(kd, tc[q], acc[8 + q]);
                acc[12 + q] = fmaf(kd, td[q], acc[12 + q]);
            }
        }
        float* dst = SUt_g + (size_t)(c*NVH + h)*64*64;
        #pragma unroll
        for (int sj = 0; sj < 16; ++sj)
            dst[(sbase + sj)*64 + d] = acc[sj];
    }
}

// ---------------------------------------------------------------------------
// Kernel 3 (phase 2): sequential over 32 chunks; block = (head, 4-col slice).
// 512 blocks -> 2 blocks/CU (2 waves/SIMD) with independent per-block phase
// timing (no inter-block barriers). T14 reg->LDS staging as in R5.
// Waves: mv = wv>>1 (0: P/o path via KT,MTt; 1: O1/state path via QT,SUt),
// jb = (wv&1)*2: 2-col group within the 4-col slice.
// ---------------------------------------------------------------------------
__global__ __launch_bounds__(256) void phase2_kernel(
    const float* __restrict__ vbp, const float* __restrict__ gam_g,
    const float* __restrict__ bg_g, const float* __restrict__ KT_g,
    const float* __restrict__ QT_g, const float* __restrict__ MTt_g,
    const float* __restrict__ SUt_g, const float* __restrict__ rs0,
    float* __restrict__ out)
{
    const int bid = blockIdx.x;
    const int h = bid & 31, jg = bid >> 5, kh = h >> 1;   // jg: 0..15, 4 cols
    const int tid = threadIdx.x, lane = tid & 63, wv = tid >> 6;
    const int mv = wv >> 1;
    const int jb = (wv & 1) * 2;

    __shared__ float bufA[8192];     // [0..4096)=KT(c), [4096..8192)=QT(c)
    __shared__ float bufB[8192];     // [0..4096)=MTt(c), [4096..8192)=SUt(c)
    __shared__ float s0s[64][6], wshs[64][6], o1s[64][6];

    // init state slice s0s[d][0..3]
    {
        int d = tid >> 2, j = tid & 3;
        s0s[d][j] = rs0[((size_t)h*64 + d)*64 + jg*4 + j];
    }

    const int base = tid * 4;   // staging offset within a 1024-float segment

    // prologue: issue rA = KT/QT(chunk 0)
    fl4 rA0, rA1, rA2, rA3, rA4, rA5, rA6, rA7;
    {
        const float* kt = KT_g + (size_t)kh * 4096 + base;
        const float* qt = QT_g + (size_t)kh * 4096 + base;
        rA0 = *(const fl4*)(kt);        rA1 = *(const fl4*)(kt + 1024);
        rA2 = *(const fl4*)(kt + 2048); rA3 = *(const fl4*)(kt + 3072);
        rA4 = *(const fl4*)(qt);        rA5 = *(const fl4*)(qt + 1024);
        rA6 = *(const fl4*)(qt + 2048); rA7 = *(const fl4*)(qt + 3072);
    }

    for (int c = 0; c < NCHUNK; ++c) {
        // write rA -> bufA (compiler inserts vmcnt wait on rA)
        *(fl4*)&bufA[base       ] = rA0; *(fl4*)&bufA[base + 1024] = rA1;
        *(fl4*)&bufA[base + 2048] = rA2; *(fl4*)&bufA[base + 3072] = rA3;
        *(fl4*)&bufA[base + 4096] = rA4; *(fl4*)&bufA[base + 5120] = rA5;
        *(fl4*)&bufA[base + 6144] = rA6; *(fl4*)&bufA[base + 7168] = rA7;

        // issue rB = MTt/SUt(c)
        fl4 rB0, rB1, rB2, rB3, rB4, rB5, rB6, rB7;
        {
            const float* mt = MTt_g + (size_t)(c*NVH + h)*4096 + base;
            const float* su = SUt_g + (size_t)(c*NVH + h)*4096 + base;
            rB0 = *(const fl4*)(mt);        rB1 = *(const fl4*)(mt + 1024);
            rB2 = *(const fl4*)(mt + 2048); rB3 = *(const fl4*)(mt + 3072);
            rB4 = *(const fl4*)(su);        rB5 = *(const fl4*)(su + 1024);
            rB6 = *(const fl4*)(su + 2048); rB7 = *(const fl4*)(su + 3072);
        }

        // per-chunk scalars
        const float* gamc = gam_g + (size_t)(c*NVH + h)*64;
        const float* bgc  = bg_g  + (size_t)(c*NVH + h)*64;
        const float gend = gamc[63];
        float vb0 = 0.f, vb1 = 0.f, bgl = 0.f, gml = 0.f;
        if (mv == 0) {
            const float* vp = &vbp[(size_t)(c*64 + lane)*VAL_DIM + h*64 + jg*4 + jb];
            vb0 = vp[0]; vb1 = vp[1];
            bgl = bgc[lane];
        } else {
            gml = gamc[lane];
        }

        __syncthreads();   // bufA visible; s0s stable

        // ---- Phase A: mv0: P via KT; mv1: O1 via QT ----
        float sa0 = s0s[lane][jb], sa1 = s0s[lane][jb + 1];
        float a0 = 0.f, a1 = 0.f;
        {
            const float* mb = &bufA[mv * 4096 + lane];
            #pragma unroll
            for (int i = 0; i < 64; ++i) {
                float m = mb[i * 64];
                a0 = fmaf(m, rdlane(sa0, i), a0);
                a1 = fmaf(m, rdlane(sa1, i), a1);
            }
        }
        if (mv == 0) {
            wshs[lane][jb]     = vb0 - bgl * a0;
            wshs[lane][jb + 1] = vb1 - bgl * a1;
        } else {
            o1s[lane][jb]     = gml * a0;
            o1s[lane][jb + 1] = gml * a1;
        }
        __syncthreads();   // wshs/o1s visible; bufA reads done

        // write rB -> bufB
        *(fl4*)&bufB[base       ] = rB0; *(fl4*)&bufB[base + 1024] = rB1;
        *(fl4*)&bufB[base + 2048] = rB2; *(fl4*)&bufB[base + 3072] = rB3;
        *(fl4*)&bufB[base + 4096] = rB4; *(fl4*)&bufB[base + 5120] = rB5;
        *(fl4*)&bufB[base + 6144] = rB6; *(fl4*)&bufB[base + 7168] = rB7;

        // issue rA = KT/QT(c+1)
        if (c + 1 < NCHUNK) {
            const float* kt = KT_g + (size_t)((c+1)*NKH + kh)*4096 + base;
            const float* qt = QT_g + (size_t)((c+1)*NKH + kh)*4096 + base;
            rA0 = *(const fl4*)(kt);        rA1 = *(const fl4*)(kt + 1024);
            rA2 = *(const fl4*)(kt + 2048); rA3 = *(const fl4*)(kt + 3072);
            rA4 = *(const fl4*)(qt);        rA5 = *(const fl4*)(qt + 1024);
            rA6 = *(const fl4*)(qt + 2048); rA7 = *(const fl4*)(qt + 3072);
        }
        __syncthreads();   // bufB visible

        // ---- Phase B: mv0: o via MTt; mv1: state update via SUt ----
        float sb0 = wshs[lane][jb], sb1 = wshs[lane][jb + 1];
        float b0 = 0.f, b1 = 0.f;
        {
            const float* mb = &bufB[mv * 4096 + lane];
            #pragma unroll
            for (int i = 0; i < 64; ++i) {
                float m = mb[i * 64];
                b0 = fmaf(m, rdlane(sb0, i), b0);
                b1 = fmaf(m, rdlane(sb1, i), b1);
            }
        }
        if (mv == 0) {
            float* op = &out[(size_t)(c*64 + lane)*VAL_DIM + h*64 + jg*4 + jb];
            op[0] = o1s[lane][jb]     + b0;
            op[1] = o1s[lane][jb + 1] + b1;
        } else {
            s0s[lane][jb]     = gend * s0s[lane][jb]     + b0;
            s0s[lane][jb + 1] = gend * s0s[lane][jb + 1] + b1;
        }
        __syncthreads();   // s0s updated for next chunk
    }
}

// ---------------------------------------------------------------------------
// Fallback: sequential scan (only if ws too small). Uses vb (=beta*v).
// ---------------------------------------------------------------------------
#define LOADSTEP(KA, QA, VV, GG, BB, tt) {                                     \
    _Pragma("unroll")                                                          \
    for (int i = 0; i < 4; ++i) {                                              \
        KA[i] = *(const fl4*)(kp + (size_t)(tt) * KEY_DIM + i * 4);            \
        QA[i] = *(const fl4*)(qp + (size_t)(tt) * KEY_DIM + i * 4);            \
    }                                                                          \
    VV = vp[(size_t)(tt) * VAL_DIM];                                           \
    GG = gp[(size_t)(tt) * NVH];                                               \
    BB = bp[(size_t)(tt) * NVH];                                               \
}

#define COMPUTE(KA, QA, VV, GG, BB, tt) {                                      \
    const float dec = __expf(GG);                                              \
    float c0 = 0.f, c1 = 0.f, c2 = 0.f, c3 = 0.f;                              \
    _Pragma("unroll")                                                          \
    for (int i = 0; i < 4; ++i) {                                              \
        S[i*4+0] *= dec; S[i*4+1] *= dec; S[i*4+2] *= dec; S[i*4+3] *= dec;    \
        c0 = fmaf(S[i*4+0], KA[i][0], c0);                                     \
        c1 = fmaf(S[i*4+1], KA[i][1], c1);                                     \
        c2 = fmaf(S[i*4+2], KA[i][2], c2);                                     \
        c3 = fmaf(S[i*4+3], KA[i][3], c3);                                     \
    }                                                                          \
    float kv = (c0 + c1) + (c2 + c3);                                          \
    kv += __shfl_xor(kv, 1);                                                   \
    kv += __shfl_xor(kv, 2);                                                   \
    const float u = VV - BB * kv;                                              \
    float o0 = 0.f, o1 = 0.f, o2 = 0.f, o3 = 0.f;                              \
    _Pragma("unroll")                                                          \
    for (int i = 0; i < 4; ++i) {                                              \
        S[i*4+0] = fmaf(KA[i][0], u, S[i*4+0]);                                \
        S[i*4+1] = fmaf(KA[i][1], u, S[i*4+1]);                                \
        S[i*4+2] = fmaf(KA[i][2], u, S[i*4+2]);                                \
        S[i*4+3] = fmaf(KA[i][3], u, S[i*4+3]);                                \
        o0 = fmaf(S[i*4+0], QA[i][0], o0);                                     \
        o1 = fmaf(S[i*4+1], QA[i][1], o1);                                     \
        o2 = fmaf(S[i*4+2], QA[i][2], o2);                                     \
        o3 = fmaf(S[i*4+3], QA[i][3], o3);                                     \
    }                                                                          \
    float oo = (o0 + o1) + (o2 + o3);                                          \
    oo += __shfl_xor(oo, 1);                                                   \
    oo += __shfl_xor(oo, 2);                                                   \
    if (kg == 0) op[(size_t)(tt) * VAL_DIM] = oo;                              \
}

__global__ __launch_bounds__(256) void scan_kernel(
    const float* __restrict__ qn, const float* __restrict__ kn,
    const float* __restrict__ v, const float* __restrict__ g,
    const float* __restrict__ bet, const float* __restrict__ rs0,
    float* __restrict__ out)
{
    const int h    = blockIdx.x;
    const int kh   = h >> 1;
    const int tid  = threadIdx.x;
    const int vcol = tid >> 2;
    const int kg   = tid & 3;

    float S[16];
    #pragma unroll
    for (int j = 0; j < 16; ++j)
        S[j] = rs0[((size_t)h * HD + (kg * 16 + j)) * HD + vcol];

    const float* kp = kn + (size_t)kh * HD + kg * 16;
    const float* qp = qn + (size_t)kh * HD + kg * 16;
    const float* vp = v + (size_t)h * HD + vcol;
    const float* gp = g + h;
    const float* bp = bet + h;
    float*       op = out + (size_t)h * HD + vcol;

    fl4 ka0[4], qa0[4]; float vv0, gg0, bb0;
    fl4 ka1[4], qa1[4]; float vv1, gg1, bb1;

    LOADSTEP(ka0, qa0, vv0, gg0, bb0, 0);
    for (int t = 0; t < T_LEN; t += 2) {
        LOADSTEP(ka1, qa1, vv1, gg1, bb1, t + 1);
        COMPUTE(ka0, qa0, vv0, gg0, bb0, t);
        const int t2 = (t + 2 < T_LEN) ? (t + 2) : (T_LEN - 1);
        LOADSTEP(ka0, qa0, vv0, gg0, bb0, t2);
        COMPUTE(ka1, qa1, vv1, gg1, bb1, t + 1);
    }
}

// ---------------------------------------------------------------------------
extern "C" void kernel_launch(void* const* d_in, const int* in_sizes, int n_in,
                              void* d_out, int out_size, void* d_ws, size_t ws_size,
                              hipStream_t stream)
{
    const float* x       = (const float*)d_in[0];
    const float* cs      = (const float*)d_in[1];
    const float* rs0     = (const float*)d_in[2];
    const float* b       = (const float*)d_in[3];
    const float* a       = (const float*)d_in[4];
    const float* w       = (const float*)d_in[5];
    const float* A_log   = (const float*)d_in[6];
    const float* dt_bias = (const float*)d_in[7];
    float* out = (float*)d_out;

    float* ws = (float*)d_ws;
    size_t off = 0;
    float* qn  = ws + off; off += (size_t)T_LEN * KEY_DIM;
    float* kn  = ws + off; off += (size_t)T_LEN * KEY_DIM;
    float* vb  = ws + off; off += (size_t)T_LEN * VAL_DIM;
    float* g   = ws + off; off += (size_t)T_LEN * NVH;
    float* be  = ws + off; off += (size_t)T_LEN * NVH;
    float* gam = ws + off; off += (size_t)NCHUNK * NVH * 64;
    float* bg  = ws + off; off += (size_t)NCHUNK * NVH * 64;
    float* KT  = ws + off; off += (size_t)NCHUNK * NKH * 64 * 64;
    float* QT  = ws + off; off += (size_t)NCHUNK * NKH * 64 * 64;
    float* MTt = ws + off; off += (size_t)NCHUNK * NVH * 64 * 64;
    float* SUt = ws + off; off += (size_t)NCHUNK * NVH * 64 * 64;
    const size_t need = off * sizeof(float);

    prep_kernel<<<T_LEN, 256, 0, stream>>>(x, cs, w, b, a, A_log, dt_bias,
                                           qn, kn, vb, g, be);
    if (ws_size >= need) {
        phase1_kernel<<<NCHUNK * NVH, 256, 0, stream>>>(qn, kn, g, be,
                                                        gam, bg, KT, QT, MTt, SUt);
        phase2_kernel<<<NVH * 16, 256, 0, stream>>>(vb, gam, bg, KT, QT, MTt, SUt,
                                                    rs0, out);
    } else {
        scan_kernel<<<NVH, 256, 0, stream>>>(qn, kn, vb, g, be, rs0, out);
    }
}

// Round 7
// 283.888 us; speedup vs baseline: 1.0724x; 1.0724x over previous
//
#include <hip/hip_runtime.h>
#include <math.h>

#define T_LEN   2048
#define NKH     16
#define NVH     32
#define HD      64
#define KEY_DIM 1024
#define VAL_DIM 2048
#define CONV_DIM 4096
#define NCHUNK  32
#define CL      64

typedef float fl4 __attribute__((ext_vector_type(4)));

__device__ __forceinline__ float sigmoid_f(float x) { return 1.f / (1.f + __expf(-x)); }
__device__ __forceinline__ float rdlane(float v, int i) {
    return __int_as_float(__builtin_amdgcn_readlane(__float_as_int(v), i));
}

// ---------------------------------------------------------------------------
// Kernel 1: causal conv1d (W=4) + silu + head split + qk l2norm + gates.
// v output is pre-scaled by beta (the only consumer of v is beta*v).
// ---------------------------------------------------------------------------
__global__ __launch_bounds__(256) void prep_kernel(
    const float* __restrict__ x,        // [T, 4096]
    const float* __restrict__ cs,       // [3, 4096]
    const float* __restrict__ w,        // [4096, 4]
    const float* __restrict__ bsrc,     // [T, 32]
    const float* __restrict__ a,        // [T, 32]
    const float* __restrict__ A_log,    // [32]
    const float* __restrict__ dt_bias,  // [32]
    float* __restrict__ qn,             // [T, 16, 64]
    float* __restrict__ kn,             // [T, 16, 64]
    float* __restrict__ vb,             // [T, 32, 64]  beta*v
    float* __restrict__ g,              // [T, 32]
    float* __restrict__ beta)           // [T, 32]
{
    const int t   = blockIdx.x;
    const int tid = threadIdx.x;
    const int d0  = tid * 16;

    fl4 r4[4];
    #pragma unroll
    for (int grp = 0; grp < 4; ++grp) {
        const int d = d0 + grp * 4;
        fl4 xv[4], wq[4];
        #pragma unroll
        for (int wi = 0; wi < 4; ++wi) {
            const int row = t - 3 + wi;
            const float* src = (row >= 0) ? (x + (size_t)row * CONV_DIM + d)
                                          : (cs + (size_t)(row + 3) * CONV_DIM + d);
            xv[wi] = *(const fl4*)src;
        }
        #pragma unroll
        for (int j = 0; j < 4; ++j) wq[j] = *(const fl4*)(w + (size_t)(d + j) * 4);
        #pragma unroll
        for (int j = 0; j < 4; ++j) {
            float acc = xv[0][j] * wq[j][0];
            acc = fmaf(xv[1][j], wq[j][1], acc);
            acc = fmaf(xv[2][j], wq[j][2], acc);
            acc = fmaf(xv[3][j], wq[j][3], acc);
            r4[grp][j] = acc * sigmoid_f(acc);
        }
    }

    if (tid < 128) {
        float ss = 0.f;
        #pragma unroll
        for (int grp = 0; grp < 4; ++grp)
            #pragma unroll
            for (int j = 0; j < 4; ++j) ss = fmaf(r4[grp][j], r4[grp][j], ss);
        ss += __shfl_xor(ss, 1);
        ss += __shfl_xor(ss, 2);
        const bool is_q = (tid < 64);
        float scale = (is_q ? 0.125f : 1.0f) / sqrtf(ss + 1e-6f);
        float* dst = is_q ? (qn + (size_t)t * KEY_DIM + d0)
                          : (kn + (size_t)t * KEY_DIM + (d0 - KEY_DIM));
        #pragma unroll
        for (int grp = 0; grp < 4; ++grp) {
            fl4 o;
            #pragma unroll
            for (int j = 0; j < 4; ++j) o[j] = r4[grp][j] * scale;
            *(fl4*)(dst + grp * 4) = o;
        }
    } else {
        const int hh = (d0 - 2 * KEY_DIM) >> 6;
        const float bb = sigmoid_f(bsrc[(size_t)t * NVH + hh]);
        float* dst = vb + (size_t)t * VAL_DIM + (d0 - 2 * KEY_DIM);
        #pragma unroll
        for (int grp = 0; grp < 4; ++grp) {
            fl4 o;
            #pragma unroll
            for (int j = 0; j < 4; ++j) o[j] = r4[grp][j] * bb;
            *(fl4*)(dst + grp * 4) = o;
        }
    }

    if (tid < 32) {
        float av = a[(size_t)t * NVH + tid] + dt_bias[tid];
        float sp = fmaxf(av, 0.f) + log1pf(__expf(-fabsf(av)));
        g[(size_t)t * NVH + tid]    = -__expf(A_log[tid]) * sp;
        beta[(size_t)t * NVH + tid] = sigmoid_f(bsrc[(size_t)t * NVH + tid]);
    }
}

// ---------------------------------------------------------------------------
// Kernel 2 (phase 1): per (chunk c, v-head h), fully parallel.
// Diagonal tri-solve now in registers (lane s holds T-column s; A read via
// wave-uniform broadcast ds_read) — removes the serial LDS dependence chain.
// ---------------------------------------------------------------------------
__global__ __launch_bounds__(256) void phase1_kernel(
    const float* __restrict__ qn, const float* __restrict__ kn,
    const float* __restrict__ gws, const float* __restrict__ bws,
    float* __restrict__ gam_g, float* __restrict__ bg_g,
    float* __restrict__ KT_g, float* __restrict__ QT_g,
    float* __restrict__ MTt_g, float* __restrict__ SUt_g)
{
    const int bid = blockIdx.x;
    const int c = bid >> 5, h = bid & 31, kh = h >> 1;
    const int tid = threadIdx.x, lane = tid & 63, wv = tid >> 6;

    __shared__ float Ks[64][68], Qs[64][68], Am[64][68], Tm[64][68];
    __shared__ float Gs[64], Dend[64], Bet[64];
    __shared__ float Xs[4][16][17];

    #pragma unroll
    for (int p = 0; p < 4; ++p) {
        int idx = p * 256 + tid;
        int t = idx >> 4, i4 = (idx & 15) * 4;
        *(fl4*)&Ks[t][i4] = *(const fl4*)&kn[(size_t)(c*64+t)*KEY_DIM + kh*64 + i4];
        *(fl4*)&Qs[t][i4] = *(const fl4*)&qn[(size_t)(c*64+t)*KEY_DIM + kh*64 + i4];
    }
    for (int idx = tid; idx < 64*64; idx += 256) {
        int t = idx >> 6, s = idx & 63;
        Tm[t][s] = (t == s) ? 1.f : 0.f;
    }
    if (tid < 64) {
        float gv = gws[(size_t)(c*64+lane)*NVH + h];
        #pragma unroll
        for (int d = 1; d < 64; d <<= 1) {
            float nv = __shfl_up(gv, d);
            if (lane >= d) gv += nv;
        }
        Gs[lane] = gv;
        float g63 = __shfl(gv, 63);
        Dend[lane] = __expf(g63 - gv);
        float bb = bws[(size_t)(c*64+lane)*NVH + h];
        Bet[lane] = bb;
        float ga = __expf(gv);
        gam_g[(size_t)(c*NVH+h)*64 + lane] = ga;
        bg_g[(size_t)(c*NVH+h)*64 + lane]  = ga * bb;
    }
    __syncthreads();

    if ((h & 1) == 0) {
        float* kdst = KT_g + (size_t)(c*NKH + kh)*64*64;
        float* qdst = QT_g + (size_t)(c*NKH + kh)*64*64;
        const int t = lane;
        #pragma unroll
        for (int ii = 0; ii < 16; ++ii) {
            int i = wv*16 + ii;
            kdst[i*64 + t] = Ks[t][i];
            qdst[i*64 + t] = Qs[t][i];
        }
    }

    float accK[16], accQ[16];
    {
        #pragma unroll
        for (int j = 0; j < 16; ++j) { accK[j] = 0.f; accQ[j] = 0.f; }
        const int t = lane, sbase = wv * 16;
        for (int i4 = 0; i4 < 64; i4 += 4) {
            fl4 kt = *(const fl4*)&Ks[t][i4];
            fl4 qt = *(const fl4*)&Qs[t][i4];
            #pragma unroll
            for (int sj = 0; sj < 16; ++sj) {
                fl4 ks = *(const fl4*)&Ks[sbase + sj][i4];
                accK[sj] += kt[0]*ks[0] + kt[1]*ks[1] + kt[2]*ks[2] + kt[3]*ks[3];
                accQ[sj] += qt[0]*ks[0] + qt[1]*ks[1] + qt[2]*ks[2] + qt[3]*ks[3];
            }
        }
    }
    __syncthreads();
    {
        const int t = lane, sbase = wv * 16;
        const float gt = Gs[t], bt = Bet[t];
        #pragma unroll
        for (int sj = 0; sj < 16; ++sj) {
            int s = sbase + sj;
            float e = __expf(gt - Gs[s]);
            Am[t][s] = (s < t)  ? bt * e * accK[sj] : 0.f;
            Qs[t][s] = (s <= t) ? e * accQ[sj] : 0.f;   // M in-place
        }
    }
    __syncthreads();

    // T = (I+A)^{-1} diagonal 16x16 blocks: register forward substitution.
    // Lane s (=lane&15) holds T-column s of its wave's block in Tc[16].
    // A entries are wave-uniform LDS reads (broadcast, no serial chain).
    {
        const int base = wv * 16;
        const int s = lane & 15;
        float Tc[16];
        #pragma unroll
        for (int j = 0; j < 16; ++j) Tc[j] = (j == s) ? 1.f : 0.f;
        #pragma unroll
        for (int t = 1; t < 16; ++t) {
            float acc = 0.f;
            #pragma unroll
            for (int il = 0; il < 16; ++il) {
                if (il < t) acc = fmaf(Am[base + t][base + il], Tc[il], acc);
            }
            Tc[t] = (s < t) ? -acc : Tc[t];
        }
        if (lane < 16) {
            #pragma unroll
            for (int j = 0; j < 16; ++j)
                Tm[base + j][base + s] = Tc[j];
        }
    }
    for (int L = 1; L <= 3; ++L) {
        __syncthreads();
        if (wv < 4 - L) {
            const int J = wv, I = wv + L;
            const int r = lane & 15, cg = lane >> 4;
            float X[4] = {0.f,0.f,0.f,0.f};
            for (int Kb = J; Kb < I; ++Kb) {
                #pragma unroll
                for (int p = 0; p < 16; ++p) {
                    float av = Am[I*16 + r][Kb*16 + p];
                    #pragma unroll
                    for (int mm = 0; mm < 4; ++mm)
                        X[mm] += av * Tm[Kb*16 + p][J*16 + cg + 4*mm];
                }
            }
            #pragma unroll
            for (int mm = 0; mm < 4; ++mm) Xs[wv][r][cg + 4*mm] = X[mm];
            float Y[4] = {0.f,0.f,0.f,0.f};
            #pragma unroll
            for (int p = 0; p < 16; ++p) {
                float td = Tm[I*16 + r][I*16 + p];
                #pragma unroll
                for (int mm = 0; mm < 4; ++mm)
                    Y[mm] += td * Xs[wv][p][cg + 4*mm];
            }
            #pragma unroll
            for (int mm = 0; mm < 4; ++mm)
                Tm[I*16 + r][J*16 + cg + 4*mm] = -Y[mm];
        }
    }
    __syncthreads();

    // MTt[s][t] = (M * T)[t][s]; M lives in Qs.  Uniform fl4 Tm reads.
    {
        float acc[16];
        #pragma unroll
        for (int j = 0; j < 16; ++j) acc[j] = 0.f;
        const int t = lane, sbase = wv * 16;
        for (int i = 0; i < 64; i += 4) {
            fl4 mv4 = *(const fl4*)&Qs[t][i];
            #pragma unroll
            for (int r = 0; r < 4; ++r) {
                fl4 ta = *(const fl4*)&Tm[i+r][sbase + 0];
                fl4 tb = *(const fl4*)&Tm[i+r][sbase + 4];
                fl4 tc = *(const fl4*)&Tm[i+r][sbase + 8];
                fl4 td = *(const fl4*)&Tm[i+r][sbase + 12];
                #pragma unroll
                for (int q = 0; q < 4; ++q) {
                    acc[q]      = fmaf(mv4[r], ta[q], acc[q]);
                    acc[4 + q]  = fmaf(mv4[r], tb[q], acc[4 + q]);
                    acc[8 + q]  = fmaf(mv4[r], tc[q], acc[8 + q]);
                    acc[12 + q] = fmaf(mv4[r], td[q], acc[12 + q]);
                }
            }
        }
        float* dst = MTt_g + (size_t)(c*NVH + h)*64*64;
        #pragma unroll
        for (int sj = 0; sj < 16; ++sj)
            dst[(sbase + sj)*64 + t] = acc[sj];
    }
    // SUt[s][d] = sum_t Dend[t]*K[t][d]*Tm[t][s].  Uniform fl4 Tm reads.
    {
        float acc[16];
        #pragma unroll
        for (int j = 0; j < 16; ++j) acc[j] = 0.f;
        const int d = lane, sbase = wv * 16;
        for (int t = 0; t < 64; ++t) {
            float kd = Ks[t][d] * Dend[t];
            fl4 ta = *(const fl4*)&Tm[t][sbase + 0];
            fl4 tb = *(const fl4*)&Tm[t][sbase + 4];
            fl4 tc = *(const fl4*)&Tm[t][sbase + 8];
            fl4 td = *(const fl4*)&Tm[t][sbase + 12];
            #pragma unroll
            for (int q = 0; q < 4; ++q) {
                acc[q]      = fmaf(kd, ta[q], acc[q]);
                acc[4 + q]  = fmaf(kd, tb[q], acc[4 + q]);
                acc[8 + q]  = fmaf(kd, tc[q], acc[8 + q]);
                acc[12 + q] = fmaf(kd, td[q], acc[12 + q]);
            }
        }
        float* dst = SUt_g + (size_t)(c*NVH + h)*64*64;
        #pragma unroll
        for (int sj = 0; sj < 16; ++sj)
            dst[(sbase + sj)*64 + d] = acc[sj];
    }
}

// ---------------------------------------------------------------------------
// Kernel 3 (phase 2): sequential over 32 chunks.
// 256 blocks (head, 8-col slice) x 512 threads (8 waves = 2 waves/SIMD):
// R5's staging amortization + R6's wave count. T14 reg->LDS staging.
// Waves: mv = wv>>2 (0: P/o path via KT,MTt; 1: O1/state path via QT,SUt),
// jb = (wv&3)*2: col pair within the 8-col slice.
// ---------------------------------------------------------------------------
__global__ __launch_bounds__(512) void phase2_kernel(
    const float* __restrict__ vbp, const float* __restrict__ gam_g,
    const float* __restrict__ bg_g, const float* __restrict__ KT_g,
    const float* __restrict__ QT_g, const float* __restrict__ MTt_g,
    const float* __restrict__ SUt_g, const float* __restrict__ rs0,
    float* __restrict__ out)
{
    const int bid = blockIdx.x;
    const int h = bid & 31, jg = bid >> 5, kh = h >> 1;   // jg: 0..7, 8 cols
    const int tid = threadIdx.x, lane = tid & 63, wv = tid >> 6;
    const int mv = wv >> 2;          // matrix select
    const int jb = (wv & 3) * 2;     // col pair

    __shared__ float bufA[8192];     // [0..4096)=KT(c), [4096..8192)=QT(c)
    __shared__ float bufB[8192];     // [0..4096)=MTt(c), [4096..8192)=SUt(c)
    __shared__ float s0s[64][9], wshs[64][9], o1s[64][9];

    // init state slice s0s[d][0..7]
    {
        int d = tid >> 3, j = tid & 7;
        s0s[d][j] = rs0[((size_t)h*64 + d)*64 + jg*8 + j];
    }

    const int base = tid * 4;   // staging offset (floats), 0..2044

    // prologue: issue rA = KT/QT(chunk 0); 2 fl4 per half-buffer per thread
    fl4 rA0, rA1, rA2, rA3;
    {
        const float* kt = KT_g + (size_t)kh * 4096 + base;
        const float* qt = QT_g + (size_t)kh * 4096 + base;
        rA0 = *(const fl4*)(kt); rA1 = *(const fl4*)(kt + 2048);
        rA2 = *(const fl4*)(qt); rA3 = *(const fl4*)(qt + 2048);
    }

    for (int c = 0; c < NCHUNK; ++c) {
        // write rA -> bufA (compiler inserts vmcnt wait on rA)
        *(fl4*)&bufA[base       ] = rA0; *(fl4*)&bufA[base + 2048] = rA1;
        *(fl4*)&bufA[base + 4096] = rA2; *(fl4*)&bufA[base + 6144] = rA3;

        // issue rB = MTt/SUt(c)
        fl4 rB0, rB1, rB2, rB3;
        {
            const float* mt = MTt_g + (size_t)(c*NVH + h)*4096 + base;
            const float* su = SUt_g + (size_t)(c*NVH + h)*4096 + base;
            rB0 = *(const fl4*)(mt); rB1 = *(const fl4*)(mt + 2048);
            rB2 = *(const fl4*)(su); rB3 = *(const fl4*)(su + 2048);
        }

        // per-chunk scalars
        const float* gamc = gam_g + (size_t)(c*NVH + h)*64;
        const float* bgc  = bg_g  + (size_t)(c*NVH + h)*64;
        const float gend = gamc[63];
        float vb0 = 0.f, vb1 = 0.f, bgl = 0.f, gml = 0.f;
        if (mv == 0) {
            const float* vp = &vbp[(size_t)(c*64 + lane)*VAL_DIM + h*64 + jg*8 + jb];
            vb0 = vp[0]; vb1 = vp[1];
            bgl = bgc[lane];
        } else {
            gml = gamc[lane];
        }

        __syncthreads();   // #1: bufA visible; s0s stable

        // ---- Phase A: mv0: P via KT; mv1: O1 via QT ----
        float sa0 = s0s[lane][jb], sa1 = s0s[lane][jb + 1];
        float a0 = 0.f, a1 = 0.f;
        {
            const float* mb = &bufA[mv * 4096 + lane];
            #pragma unroll
            for (int i = 0; i < 64; ++i) {
                float m = mb[i * 64];
                a0 = fmaf(m, rdlane(sa0, i), a0);
                a1 = fmaf(m, rdlane(sa1, i), a1);
            }
        }
        if (mv == 0) {
            wshs[lane][jb]     = vb0 - bgl * a0;
            wshs[lane][jb + 1] = vb1 - bgl * a1;
        } else {
            o1s[lane][jb]     = gml * a0;
            o1s[lane][jb + 1] = gml * a1;
        }
        __syncthreads();   // #2: wshs/o1s visible; bufA reads done

        // write rB -> bufB
        *(fl4*)&bufB[base       ] = rB0; *(fl4*)&bufB[base + 2048] = rB1;
        *(fl4*)&bufB[base + 4096] = rB2; *(fl4*)&bufB[base + 6144] = rB3;

        // issue rA = KT/QT(c+1)
        if (c + 1 < NCHUNK) {
            const float* kt = KT_g + (size_t)((c+1)*NKH + kh)*4096 + base;
            const float* qt = QT_g + (size_t)((c+1)*NKH + kh)*4096 + base;
            rA0 = *(const fl4*)(kt); rA1 = *(const fl4*)(kt + 2048);
            rA2 = *(const fl4*)(qt); rA3 = *(const fl4*)(qt + 2048);
        }
        __syncthreads();   // #3: bufB visible

        // ---- Phase B: mv0: o via MTt; mv1: state update via SUt ----
        float sb0 = wshs[lane][jb], sb1 = wshs[lane][jb + 1];
        float b0 = 0.f, b1 = 0.f;
        {
            const float* mb = &bufB[mv * 4096 + lane];
            #pragma unroll
            for (int i = 0; i < 64; ++i) {
                float m = mb[i * 64];
                b0 = fmaf(m, rdlane(sb0, i), b0);
                b1 = fmaf(m, rdlane(sb1, i), b1);
            }
        }
        if (mv == 0) {
            float* op = &out[(size_t)(c*64 + lane)*VAL_DIM + h*64 + jg*8 + jb];
            op[0] = o1s[lane][jb]     + b0;
            op[1] = o1s[lane][jb + 1] + b1;
        } else {
            s0s[lane][jb]     = gend * s0s[lane][jb]     + b0;
            s0s[lane][jb + 1] = gend * s0s[lane][jb + 1] + b1;
        }
        __syncthreads();   // #4: s0s updated for next chunk
    }
}

// ---------------------------------------------------------------------------
// Fallback: sequential scan (only if ws too small). Uses vb (=beta*v).
// ---------------------------------------------------------------------------
#define LOADSTEP(KA, QA, VV, GG, BB, tt) {                                     \
    _Pragma("unroll")                                                          \
    for (int i = 0; i < 4; ++i) {                                              \
        KA[i] = *(const fl4*)(kp + (size_t)(tt) * KEY_DIM + i * 4);            \
        QA[i] = *(const fl4*)(qp + (size_t)(tt) * KEY_DIM + i * 4);            \
    }                                                                          \
    VV = vp[(size_t)(tt) * VAL_DIM];                                           \
    GG = gp[(size_t)(tt) * NVH];                                               \
    BB = bp[(size_t)(tt) * NVH];                                               \
}

#define COMPUTE(KA, QA, VV, GG, BB, tt) {                                      \
    const float dec = __expf(GG);                                              \
    float c0 = 0.f, c1 = 0.f, c2 = 0.f, c3 = 0.f;                              \
    _Pragma("unroll")                                                          \
    for (int i = 0; i < 4; ++i) {                                              \
        S[i*4+0] *= dec; S[i*4+1] *= dec; S[i*4+2] *= dec; S[i*4+3] *= dec;    \
        c0 = fmaf(S[i*4+0], KA[i][0], c0);                                     \
        c1 = fmaf(S[i*4+1], KA[i][1], c1);                                     \
        c2 = fmaf(S[i*4+2], KA[i][2], c2);                                     \
        c3 = fmaf(S[i*4+3], KA[i][3], c3);                                     \
    }                                                                          \
    float kv = (c0 + c1) + (c2 + c3);                                          \
    kv += __shfl_xor(kv, 1);                                                   \
    kv += __shfl_xor(kv, 2);                                                   \
    const float u = VV - BB * kv;                                              \
    float o0 = 0.f, o1 = 0.f, o2 = 0.f, o3 = 0.f;                              \
    _Pragma("unroll")                                                          \
    for (int i = 0; i < 4; ++i) {                                              \
        S[i*4+0] = fmaf(KA[i][0], u, S[i*4+0]);                                \
        S[i*4+1] = fmaf(KA[i][1], u, S[i*4+1]);                                \
        S[i*4+2] = fmaf(KA[i][2], u, S[i*4+2]);                                \
        S[i*4+3] = fmaf(KA[i][3], u, S[i*4+3]);                                \
        o0 = fmaf(S[i*4+0], QA[i][0], o0);                                     \
        o1 = fmaf(S[i*4+1], QA[i][1], o1);                                     \
        o2 = fmaf(S[i*4+2], QA[i][2], o2);                                     \
        o3 = fmaf(S[i*4+3], QA[i][3], o3);                                     \
    }                                                                          \
    float oo = (o0 + o1) + (o2 + o3);                                          \
    oo += __shfl_xor(oo, 1);                                                   \
    oo += __shfl_xor(oo, 2);                                                   \
    if (kg == 0) op[(size_t)(tt) * VAL_DIM] = oo;                              \
}

__global__ __launch_bounds__(256) void scan_kernel(
    const float* __restrict__ qn, const float* __restrict__ kn,
    const float* __restrict__ v, const float* __restrict__ g,
    const float* __restrict__ bet, const float* __restrict__ rs0,
    float* __restrict__ out)
{
    const int h    = blockIdx.x;
    const int kh   = h >> 1;
    const int tid  = threadIdx.x;
    const int vcol = tid >> 2;
    const int kg   = tid & 3;

    float S[16];
    #pragma unroll
    for (int j = 0; j < 16; ++j)
        S[j] = rs0[((size_t)h * HD + (kg * 16 + j)) * HD + vcol];

    const float* kp = kn + (size_t)kh * HD + kg * 16;
    const float* qp = qn + (size_t)kh * HD + kg * 16;
    const float* vp = v + (size_t)h * HD + vcol;
    const float* gp = g + h;
    const float* bp = bet + h;
    float*       op = out + (size_t)h * HD + vcol;

    fl4 ka0[4], qa0[4]; float vv0, gg0, bb0;
    fl4 ka1[4], qa1[4]; float vv1, gg1, bb1;

    LOADSTEP(ka0, qa0, vv0, gg0, bb0, 0);
    for (int t = 0; t < T_LEN; t += 2) {
        LOADSTEP(ka1, qa1, vv1, gg1, bb1, t + 1);
        COMPUTE(ka0, qa0, vv0, gg0, bb0, t);
        const int t2 = (t + 2 < T_LEN) ? (t + 2) : (T_LEN - 1);
        LOADSTEP(ka0, qa0, vv0, gg0, bb0, t2);
        COMPUTE(ka1, qa1, vv1, gg1, bb1, t + 1);
    }
}

// ---------------------------------------------------------------------------
extern "C" void kernel_launch(void* const* d_in, const int* in_sizes, int n_in,
                              void* d_out, int out_size, void* d_ws, size_t ws_size,
                              hipStream_t stream)
{
    const float* x       = (const float*)d_in[0];
    const float* cs      = (const float*)d_in[1];
    const float* rs0     = (const float*)d_in[2];
    const float* b       = (const float*)d_in[3];
    const float* a       = (const float*)d_in[4];
    const float* w       = (const float*)d_in[5];
    const float* A_log   = (const float*)d_in[6];
    const float* dt_bias = (const float*)d_in[7];
    float* out = (float*)d_out;

    float* ws = (float*)d_ws;
    size_t off = 0;
    float* qn  = ws + off; off += (size_t)T_LEN * KEY_DIM;
    float* kn  = ws + off; off += (size_t)T_LEN * KEY_DIM;
    float* vb  = ws + off; off += (size_t)T_LEN * VAL_DIM;
    float* g   = ws + off; off += (size_t)T_LEN * NVH;
    float* be  = ws + off; off += (size_t)T_LEN * NVH;
    float* gam = ws + off; off += (size_t)NCHUNK * NVH * 64;
    float* bg  = ws + off; off += (size_t)NCHUNK * NVH * 64;
    float* KT  = ws + off; off += (size_t)NCHUNK * NKH * 64 * 64;
    float* QT  = ws + off; off += (size_t)NCHUNK * NKH * 64 * 64;
    float* MTt = ws + off; off += (size_t)NCHUNK * NVH * 64 * 64;
    float* SUt = ws + off; off += (size_t)NCHUNK * NVH * 64 * 64;
    const size_t need = off * sizeof(float);

    prep_kernel<<<T_LEN, 256, 0, stream>>>(x, cs, w, b, a, A_log, dt_bias,
                                           qn, kn, vb, g, be);
    if (ws_size >= need) {
        phase1_kernel<<<NCHUNK * NVH, 256, 0, stream>>>(qn, kn, g, be,
                                                        gam, bg, KT, QT, MTt, SUt);
        phase2_kernel<<<NVH * 8, 512, 0, stream>>>(vb, gam, bg, KT, QT, MTt, SUt,
                                                   rs0, out);
    } else {
        scan_kernel<<<NVH, 256, 0, stream>>>(qn, kn, vb, g, be, rs0, out);
    }
}

// Round 9
// 272.894 us; speedup vs baseline: 1.1156x; 1.0403x over previous
//
#include <hip/hip_runtime.h>
#include <math.h>

#define T_LEN   2048
#define NKH     16
#define NVH     32
#define HD      64
#define KEY_DIM 1024
#define VAL_DIM 2048
#define CONV_DIM 4096
#define NCHUNK  32
#define CL      64

typedef float fl4 __attribute__((ext_vector_type(4)));

__device__ __forceinline__ float sigmoid_f(float x) { return 1.f / (1.f + __expf(-x)); }
__device__ __forceinline__ float rdlane(float v, int i) {
    return __int_as_float(__builtin_amdgcn_readlane(__float_as_int(v), i));
}

// ---------------------------------------------------------------------------
// Kernel 1: causal conv1d (W=4) + silu + head split + qk l2norm + gates.
// v output is pre-scaled by beta (the only consumer of v is beta*v).
// ---------------------------------------------------------------------------
__global__ __launch_bounds__(256) void prep_kernel(
    const float* __restrict__ x,        // [T, 4096]
    const float* __restrict__ cs,       // [3, 4096]
    const float* __restrict__ w,        // [4096, 4]
    const float* __restrict__ bsrc,     // [T, 32]
    const float* __restrict__ a,        // [T, 32]
    const float* __restrict__ A_log,    // [32]
    const float* __restrict__ dt_bias,  // [32]
    float* __restrict__ qn,             // [T, 16, 64]
    float* __restrict__ kn,             // [T, 16, 64]
    float* __restrict__ vb,             // [T, 32, 64]  beta*v
    float* __restrict__ g,              // [T, 32]
    float* __restrict__ beta)           // [T, 32]
{
    const int t   = blockIdx.x;
    const int tid = threadIdx.x;
    const int d0  = tid * 16;

    fl4 r4[4];
    #pragma unroll
    for (int grp = 0; grp < 4; ++grp) {
        const int d = d0 + grp * 4;
        fl4 xv[4], wq[4];
        #pragma unroll
        for (int wi = 0; wi < 4; ++wi) {
            const int row = t - 3 + wi;
            const float* src = (row >= 0) ? (x + (size_t)row * CONV_DIM + d)
                                          : (cs + (size_t)(row + 3) * CONV_DIM + d);
            xv[wi] = *(const fl4*)src;
        }
        #pragma unroll
        for (int j = 0; j < 4; ++j) wq[j] = *(const fl4*)(w + (size_t)(d + j) * 4);
        #pragma unroll
        for (int j = 0; j < 4; ++j) {
            float acc = xv[0][j] * wq[j][0];
            acc = fmaf(xv[1][j], wq[j][1], acc);
            acc = fmaf(xv[2][j], wq[j][2], acc);
            acc = fmaf(xv[3][j], wq[j][3], acc);
            r4[grp][j] = acc * sigmoid_f(acc);
        }
    }

    if (tid < 128) {
        float ss = 0.f;
        #pragma unroll
        for (int grp = 0; grp < 4; ++grp)
            #pragma unroll
            for (int j = 0; j < 4; ++j) ss = fmaf(r4[grp][j], r4[grp][j], ss);
        ss += __shfl_xor(ss, 1);
        ss += __shfl_xor(ss, 2);
        const bool is_q = (tid < 64);
        float scale = (is_q ? 0.125f : 1.0f) / sqrtf(ss + 1e-6f);
        float* dst = is_q ? (qn + (size_t)t * KEY_DIM + d0)
                          : (kn + (size_t)t * KEY_DIM + (d0 - KEY_DIM));
        #pragma unroll
        for (int grp = 0; grp < 4; ++grp) {
            fl4 o;
            #pragma unroll
            for (int j = 0; j < 4; ++j) o[j] = r4[grp][j] * scale;
            *(fl4*)(dst + grp * 4) = o;
        }
    } else {
        const int hh = (d0 - 2 * KEY_DIM) >> 6;
        const float bb = sigmoid_f(bsrc[(size_t)t * NVH + hh]);
        float* dst = vb + (size_t)t * VAL_DIM + (d0 - 2 * KEY_DIM);
        #pragma unroll
        for (int grp = 0; grp < 4; ++grp) {
            fl4 o;
            #pragma unroll
            for (int j = 0; j < 4; ++j) o[j] = r4[grp][j] * bb;
            *(fl4*)(dst + grp * 4) = o;
        }
    }

    if (tid < 32) {
        float av = a[(size_t)t * NVH + tid] + dt_bias[tid];
        float sp = fmaxf(av, 0.f) + log1pf(__expf(-fabsf(av)));
        g[(size_t)t * NVH + tid]    = -__expf(A_log[tid]) * sp;
        beta[(size_t)t * NVH + tid] = sigmoid_f(bsrc[(size_t)t * NVH + tid]);
    }
}

// ---------------------------------------------------------------------------
// Kernel 2 (phase 1): one block per (chunk c, K-HEAD kh) — 512 blocks.
// The two v-heads h=2kh,2kh+1 share K,Q: load + KK^T + QK^T + KT/QT pack are
// done ONCE (accK/accQ live in registers); per-head gating/solve/MTt/SUt loop
// reuses the same Am/Qs/Tm LDS tiles. 2 blocks/CU, single residency round.
// ---------------------------------------------------------------------------
__global__ __launch_bounds__(256) void phase1_kernel(
    const float* __restrict__ qn, const float* __restrict__ kn,
    const float* __restrict__ gws, const float* __restrict__ bws,
    float* __restrict__ gam_g, float* __restrict__ bg_g,
    float* __restrict__ KT_g, float* __restrict__ QT_g,
    float* __restrict__ MTt_g, float* __restrict__ SUt_g)
{
    const int bid = blockIdx.x;
    const int c = bid >> 4, kh = bid & 15;
    const int tid = threadIdx.x, lane = tid & 63, wv = tid >> 6;

    __shared__ float Ks[64][68], Qs[64][68], Am[64][68], Tm[64][68];
    __shared__ float Gs[2][64], Dend[2][64], Bet[2][64];
    __shared__ float Xs[4][16][17];

    #pragma unroll
    for (int p = 0; p < 4; ++p) {
        int idx = p * 256 + tid;
        int t = idx >> 4, i4 = (idx & 15) * 4;
        *(fl4*)&Ks[t][i4] = *(const fl4*)&kn[(size_t)(c*64+t)*KEY_DIM + kh*64 + i4];
        *(fl4*)&Qs[t][i4] = *(const fl4*)&qn[(size_t)(c*64+t)*KEY_DIM + kh*64 + i4];
    }
    for (int idx = tid; idx < 64*64; idx += 256) {
        int t = idx >> 6, s = idx & 63;
        Tm[t][s] = (t == s) ? 1.f : 0.f;
    }
    // gates for BOTH heads: wave 0 -> h=2kh, wave 1 -> h=2kh+1
    if (tid < 128) {
        const int hh = wv;               // 0 or 1
        const int h = 2*kh + hh;
        float gv = gws[(size_t)(c*64+lane)*NVH + h];
        #pragma unroll
        for (int d = 1; d < 64; d <<= 1) {
            float nv = __shfl_up(gv, d);
            if (lane >= d) gv += nv;
        }
        Gs[hh][lane] = gv;
        float g63 = __shfl(gv, 63);
        Dend[hh][lane] = __expf(g63 - gv);
        float bb = bws[(size_t)(c*64+lane)*NVH + h];
        Bet[hh][lane] = bb;
        float ga = __expf(gv);
        gam_g[(size_t)(c*NVH+h)*64 + lane] = ga;
        bg_g[(size_t)(c*NVH+h)*64 + lane]  = ga * bb;
    }
    __syncthreads();

    // packed transposes (once per kh; before Qs is overwritten by M)
    {
        float* kdst = KT_g + (size_t)(c*NKH + kh)*64*64;
        float* qdst = QT_g + (size_t)(c*NKH + kh)*64*64;
        const int t = lane;
        #pragma unroll
        for (int ii = 0; ii < 16; ++ii) {
            int i = wv*16 + ii;
            kdst[i*64 + t] = Ks[t][i];
            qdst[i*64 + t] = Qs[t][i];
        }
    }

    // shared raw matmuls: accK = (K K^T) row t, accQ = (Q K^T) row t
    float accK[16], accQ[16];
    {
        #pragma unroll
        for (int j = 0; j < 16; ++j) { accK[j] = 0.f; accQ[j] = 0.f; }
        const int t = lane, sbase = wv * 16;
        for (int i4 = 0; i4 < 64; i4 += 4) {
            fl4 kt = *(const fl4*)&Ks[t][i4];
            fl4 qt = *(const fl4*)&Qs[t][i4];
            #pragma unroll
            for (int sj = 0; sj < 16; ++sj) {
                fl4 ks = *(const fl4*)&Ks[sbase + sj][i4];
                accK[sj] += kt[0]*ks[0] + kt[1]*ks[1] + kt[2]*ks[2] + kt[3]*ks[3];
                accQ[sj] += qt[0]*ks[0] + qt[1]*ks[1] + qt[2]*ks[2] + qt[3]*ks[3];
            }
        }
    }

    // per-head: gate -> solve -> MTt/SUt (Am/Qs/Tm tiles reused; Tm upper
    // blocks stay 0 across heads, diag+lower fully rewritten by each solve)
    #pragma unroll
    for (int hh = 0; hh < 2; ++hh) {
        const int h = 2*kh + hh;
        __syncthreads();   // head0: accK/accQ reads of Qs done; head1: prev MTt/SUt reads done
        {
            const int t = lane, sbase = wv * 16;
            const float gt = Gs[hh][t], bt = Bet[hh][t];
            #pragma unroll
            for (int sj = 0; sj < 16; ++sj) {
                int s = sbase + sj;
                float e = __expf(gt - Gs[hh][s]);
                Am[t][s] = (s < t)  ? bt * e * accK[sj] : 0.f;
                Qs[t][s] = (s <= t) ? e * accQ[sj] : 0.f;   // M in-place
            }
        }
        __syncthreads();

        // T = (I+A)^{-1} diagonal blocks: register forward substitution
        {
            const int base = wv * 16;
            const int s = lane & 15;
            float Tc[16];
            #pragma unroll
            for (int j = 0; j < 16; ++j) Tc[j] = (j == s) ? 1.f : 0.f;
            #pragma unroll
            for (int t = 1; t < 16; ++t) {
                float acc = 0.f;
                #pragma unroll
                for (int il = 0; il < 16; ++il) {
                    if (il < t) acc = fmaf(Am[base + t][base + il], Tc[il], acc);
                }
                Tc[t] = (s < t) ? -acc : Tc[t];
            }
            if (lane < 16) {
                #pragma unroll
                for (int j = 0; j < 16; ++j)
                    Tm[base + j][base + s] = Tc[j];
            }
        }
        for (int L = 1; L <= 3; ++L) {
            __syncthreads();
            if (wv < 4 - L) {
                const int J = wv, I = wv + L;
                const int r = lane & 15, cg = lane >> 4;
                float X[4] = {0.f,0.f,0.f,0.f};
                for (int Kb = J; Kb < I; ++Kb) {
                    #pragma unroll
                    for (int p = 0; p < 16; ++p) {
                        float av = Am[I*16 + r][Kb*16 + p];
                        #pragma unroll
                        for (int mm = 0; mm < 4; ++mm)
                            X[mm] += av * Tm[Kb*16 + p][J*16 + cg + 4*mm];
                    }
                }
                #pragma unroll
                for (int mm = 0; mm < 4; ++mm) Xs[wv][r][cg + 4*mm] = X[mm];
                float Y[4] = {0.f,0.f,0.f,0.f};
                #pragma unroll
                for (int p = 0; p < 16; ++p) {
                    float td = Tm[I*16 + r][I*16 + p];
                    #pragma unroll
                    for (int mm = 0; mm < 4; ++mm)
                        Y[mm] += td * Xs[wv][p][cg + 4*mm];
                }
                #pragma unroll
                for (int mm = 0; mm < 4; ++mm)
                    Tm[I*16 + r][J*16 + cg + 4*mm] = -Y[mm];
            }
        }
        __syncthreads();

        // MTt[s][t] = (M * T)[t][s]; M lives in Qs.  Uniform fl4 Tm reads.
        {
            float acc[16];
            #pragma unroll
            for (int j = 0; j < 16; ++j) acc[j] = 0.f;
            const int t = lane, sbase = wv * 16;
            for (int i = 0; i < 64; i += 4) {
                fl4 mv4 = *(const fl4*)&Qs[t][i];
                #pragma unroll
                for (int r = 0; r < 4; ++r) {
                    fl4 ta = *(const fl4*)&Tm[i+r][sbase + 0];
                    fl4 tb = *(const fl4*)&Tm[i+r][sbase + 4];
                    fl4 tc = *(const fl4*)&Tm[i+r][sbase + 8];
                    fl4 td = *(const fl4*)&Tm[i+r][sbase + 12];
                    #pragma unroll
                    for (int q = 0; q < 4; ++q) {
                        acc[q]      = fmaf(mv4[r], ta[q], acc[q]);
                        acc[4 + q]  = fmaf(mv4[r], tb[q], acc[4 + q]);
                        acc[8 + q]  = fmaf(mv4[r], tc[q], acc[8 + q]);
                        acc[12 + q] = fmaf(mv4[r], td[q], acc[12 + q]);
                    }
                }
            }
            float* dst = MTt_g + (size_t)(c*NVH + h)*64*64;
            #pragma unroll
            for (int sj = 0; sj < 16; ++sj)
                dst[(sbase + sj)*64 + t] = acc[sj];
        }
        // SUt[s][d] = sum_t Dend[t]*K[t][d]*Tm[t][s].  Uniform fl4 Tm reads.
        {
            float acc[16];
            #pragma unroll
            for (int j = 0; j < 16; ++j) acc[j] = 0.f;
            const int d = lane, sbase = wv * 16;
            for (int t = 0; t < 64; ++t) {
                float kd = Ks[t][d] * Dend[hh][t];
                fl4 ta = *(const fl4*)&Tm[t][sbase + 0];
                fl4 tb = *(const fl4*)&Tm[t][sbase + 4];
                fl4 tc = *(const fl4*)&Tm[t][sbase + 8];
                fl4 td = *(const fl4*)&Tm[t][sbase + 12];
                #pragma unroll
                for (int q = 0; q < 4; ++q) {
                    acc[q]      = fmaf(kd, ta[q], acc[q]);
                    acc[4 + q]  = fmaf(kd, tb[q], acc[4 + q]);
                    acc[8 + q]  = fmaf(kd, tc[q], acc[8 + q]);
                    acc[12 + q] = fmaf(kd, td[q], acc[12 + q]);
                }
            }
            float* dst = SUt_g + (size_t)(c*NVH + h)*64*64;
            #pragma unroll
            for (int sj = 0; sj < 16; ++sj)
                dst[(sbase + sj)*64 + d] = acc[sj];
        }
    }
}

// ---------------------------------------------------------------------------
// Kernel 3 (phase 2): sequential over 32 chunks.
// 256 blocks (head, 8-col slice) x 512 threads. 3 barriers/chunk; rA
// prefetched a full chunk ahead, rB ~3/4 chunk ahead; split acc chains.
// Waves: mv = wv>>2 (0: P/o path via KT,MTt; 1: O1/state path via QT,SUt),
// jb = (wv&3)*2: col pair within the 8-col slice.
// ---------------------------------------------------------------------------
__global__ __launch_bounds__(512) void phase2_kernel(
    const float* __restrict__ vbp, const float* __restrict__ gam_g,
    const float* __restrict__ bg_g, const float* __restrict__ KT_g,
    const float* __restrict__ QT_g, const float* __restrict__ MTt_g,
    const float* __restrict__ SUt_g, const float* __restrict__ rs0,
    float* __restrict__ out)
{
    const int bid = blockIdx.x;
    const int h = bid & 31, jg = bid >> 5, kh = h >> 1;   // jg: 0..7, 8 cols
    const int tid = threadIdx.x, lane = tid & 63, wv = tid >> 6;
    const int mv = wv >> 2;          // matrix select
    const int jb = (wv & 3) * 2;     // col pair

    __shared__ float bufA[8192];     // [0..4096)=KT(c), [4096..8192)=QT(c)
    __shared__ float bufB[8192];     // [0..4096)=MTt(c), [4096..8192)=SUt(c)
    __shared__ float s0s[64][9], wshs[64][9], o1s[64][9];

    // init state slice s0s[d][0..7]
    {
        int d = tid >> 3, j = tid & 7;
        s0s[d][j] = rs0[((size_t)h*64 + d)*64 + jg*8 + j];
    }

    const int base = tid * 4;   // staging offset (floats), 0..2044

    // prologue: issue rA(0) and rB(0)
    fl4 rA0, rA1, rA2, rA3, rB0, rB1, rB2, rB3;
    {
        const float* kt = KT_g + (size_t)kh * 4096 + base;
        const float* qt = QT_g + (size_t)kh * 4096 + base;
        rA0 = *(const fl4*)(kt); rA1 = *(const fl4*)(kt + 2048);
        rA2 = *(const fl4*)(qt); rA3 = *(const fl4*)(qt + 2048);
        const float* mt = MTt_g + (size_t)h * 4096 + base;
        const float* su = SUt_g + (size_t)h * 4096 + base;
        rB0 = *(const fl4*)(mt); rB1 = *(const fl4*)(mt + 2048);
        rB2 = *(const fl4*)(su); rB3 = *(const fl4*)(su + 2048);
    }

    for (int c = 0; c < NCHUNK; ++c) {
        // write rA -> bufA (vmcnt wait on rA, issued one chunk ago)
        *(fl4*)&bufA[base       ] = rA0; *(fl4*)&bufA[base + 2048] = rA1;
        *(fl4*)&bufA[base + 4096] = rA2; *(fl4*)&bufA[base + 6144] = rA3;
        // issue rA(c+1) — consumed next chunk top
        if (c + 1 < NCHUNK) {
            const float* kt = KT_g + (size_t)((c+1)*NKH + kh)*4096 + base;
            const float* qt = QT_g + (size_t)((c+1)*NKH + kh)*4096 + base;
            rA0 = *(const fl4*)(kt); rA1 = *(const fl4*)(kt + 2048);
            rA2 = *(const fl4*)(qt); rA3 = *(const fl4*)(qt + 2048);
        }

        // per-chunk scalars
        const float* gamc = gam_g + (size_t)(c*NVH + h)*64;
        const float* bgc  = bg_g  + (size_t)(c*NVH + h)*64;
        const float gend = gamc[63];
        float vb0 = 0.f, vb1 = 0.f, bgl = 0.f, gml = 0.f;
        if (mv == 0) {
            const float* vp = &vbp[(size_t)(c*64 + lane)*VAL_DIM + h*64 + jg*8 + jb];
            vb0 = vp[0]; vb1 = vp[1];
            bgl = bgc[lane];
        } else {
            gml = gamc[lane];
        }

        __syncthreads();   // #1: bufA visible; s0s stable

        // ---- Phase A: mv0: P via KT; mv1: O1 via QT ----
        float sa0 = s0s[lane][jb], sa1 = s0s[lane][jb + 1];
        float a0e = 0.f, a0o = 0.f, a1e = 0.f, a1o = 0.f;
        {
            const float* mb = &bufA[mv * 4096 + lane];
            #pragma unroll
            for (int i = 0; i < 64; i += 2) {
                float m0 = mb[i * 64], m1 = mb[(i + 1) * 64];
                a0e = fmaf(m0, rdlane(sa0, i), a0e);
                a1e = fmaf(m0, rdlane(sa1, i), a1e);
                a0o = fmaf(m1, rdlane(sa0, i + 1), a0o);
                a1o = fmaf(m1, rdlane(sa1, i + 1), a1o);
            }
        }
        {
            float a0 = a0e + a0o, a1 = a1e + a1o;
            if (mv == 0) {
                wshs[lane][jb]     = vb0 - bgl * a0;
                wshs[lane][jb + 1] = vb1 - bgl * a1;
            } else {
                o1s[lane][jb]     = gml * a0;
                o1s[lane][jb + 1] = gml * a1;
            }
        }

        // write rB -> bufB (vmcnt wait on rB, issued ~3/4 chunk ago)
        *(fl4*)&bufB[base       ] = rB0; *(fl4*)&bufB[base + 2048] = rB1;
        *(fl4*)&bufB[base + 4096] = rB2; *(fl4*)&bufB[base + 6144] = rB3;
        // issue rB(c+1) — consumed next chunk mid
        if (c + 1 < NCHUNK) {
            const float* mt = MTt_g + (size_t)((c+1)*NVH + h)*4096 + base;
            const float* su = SUt_g + (size_t)((c+1)*NVH + h)*4096 + base;
            rB0 = *(const fl4*)(mt); rB1 = *(const fl4*)(mt + 2048);
            rB2 = *(const fl4*)(su); rB3 = *(const fl4*)(su + 2048);
        }
        __syncthreads();   // #2: wshs/o1s + bufB visible; bufA reads done

        // ---- Phase B: mv0: o via MTt; mv1: state update via SUt ----
        float sb0 = wshs[lane][jb], sb1 = wshs[lane][jb + 1];
        float b0e = 0.f, b0o = 0.f, b1e = 0.f, b1o = 0.f;
        {
            const float* mb = &bufB[mv * 4096 + lane];
            #pragma unroll
            for (int i = 0; i < 64; i += 2) {
                float m0 = mb[i * 64], m1 = mb[(i + 1) * 64];
                b0e = fmaf(m0, rdlane(sb0, i), b0e);
                b1e = fmaf(m0, rdlane(sb1, i), b1e);
                b0o = fmaf(m1, rdlane(sb0, i + 1), b0o);
                b1o = fmaf(m1, rdlane(sb1, i + 1), b1o);
            }
        }
        {
            float b0 = b0e + b0o, b1 = b1e + b1o;
            if (mv == 0) {
                float* op = &out[(size_t)(c*64 + lane)*VAL_DIM + h*64 + jg*8 + jb];
                op[0] = o1s[lane][jb]     + b0;
                op[1] = o1s[lane][jb + 1] + b1;
            } else {
                s0s[lane][jb]     = gend * s0s[lane][jb]     + b0;
                s0s[lane][jb + 1] = gend * s0s[lane][jb + 1] + b1;
            }
        }
        __syncthreads();   // #3: s0s updated; bufB reads done
    }
}

// ---------------------------------------------------------------------------
// Fallback: sequential scan (only if ws too small). Uses vb (=beta*v).
// ---------------------------------------------------------------------------
#define LOADSTEP(KA, QA, VV, GG, BB, tt) {                                     \
    _Pragma("unroll")                                                          \
    for (int i = 0; i < 4; ++i) {                                              \
        KA[i] = *(const fl4*)(kp + (size_t)(tt) * KEY_DIM + i * 4);            \
        QA[i] = *(const fl4*)(qp + (size_t)(tt) * KEY_DIM + i * 4);            \
    }                                                                          \
    VV = vp[(size_t)(tt) * VAL_DIM];                                           \
    GG = gp[(size_t)(tt) * NVH];                                               \
    BB = bp[(size_t)(tt) * NVH];                                               \
}

#define COMPUTE(KA, QA, VV, GG, BB, tt) {                                      \
    const float dec = __expf(GG);                                              \
    float c0 = 0.f, c1 = 0.f, c2 = 0.f, c3 = 0.f;                              \
    _Pragma("unroll")                                                          \
    for (int i = 0; i < 4; ++i) {                                              \
        S[i*4+0] *= dec; S[i*4+1] *= dec; S[i*4+2] *= dec; S[i*4+3] *= dec;    \
        c0 = fmaf(S[i*4+0], KA[i][0], c0);                                     \
        c1 = fmaf(S[i*4+1], KA[i][1], c1);                                     \
        c2 = fmaf(S[i*4+2], KA[i][2], c2);                                     \
        c3 = fmaf(S[i*4+3], KA[i][3], c3);                                     \
    }                                                                          \
    float kv = (c0 + c1) + (c2 + c3);                                          \
    kv += __shfl_xor(kv, 1);                                                   \
    kv += __shfl_xor(kv, 2);                                                   \
    const float u = VV - BB * kv;                                              \
    float o0 = 0.f, o1 = 0.f, o2 = 0.f, o3 = 0.f;                              \
    _Pragma("unroll")                                                          \
    for (int i = 0; i < 4; ++i) {                                              \
        S[i*4+0] = fmaf(KA[i][0], u, S[i*4+0]);                                \
        S[i*4+1] = fmaf(KA[i][1], u, S[i*4+1]);                                \
        S[i*4+2] = fmaf(KA[i][2], u, S[i*4+2]);                                \
        S[i*4+3] = fmaf(KA[i][3], u, S[i*4+3]);                                \
        o0 = fmaf(S[i*4+0], QA[i][0], o0);                                     \
        o1 = fmaf(S[i*4+1], QA[i][1], o1);                                     \
        o2 = fmaf(S[i*4+2], QA[i][2], o2);                                     \
        o3 = fmaf(S[i*4+3], QA[i][3], o3);                                     \
    }                                                                          \
    float oo = (o0 + o1) + (o2 + o3);                                          \
    oo += __shfl_xor(oo, 1);                                                   \
    oo += __shfl_xor(oo, 2);                                                   \
    if (kg == 0) op[(size_t)(tt) * VAL_DIM] = oo;                              \
}

__global__ __launch_bounds__(256) void scan_kernel(
    const float* __restrict__ qn, const float* __restrict__ kn,
    const float* __restrict__ v, const float* __restrict__ g,
    const float* __restrict__ bet, const float* __restrict__ rs0,
    float* __restrict__ out)
{
    const int h    = blockIdx.x;
    const int kh   = h >> 1;
    const int tid  = threadIdx.x;
    const int vcol = tid >> 2;
    const int kg   = tid & 3;

    float S[16];
    #pragma unroll
    for (int j = 0; j < 16; ++j)
        S[j] = rs0[((size_t)h * HD + (kg * 16 + j)) * HD + vcol];

    const float* kp = kn + (size_t)kh * HD + kg * 16;
    const float* qp = qn + (size_t)kh * HD + kg * 16;
    const float* vp = v + (size_t)h * HD + vcol;
    const float* gp = g + h;
    const float* bp = bet + h;
    float*       op = out + (size_t)h * HD + vcol;

    fl4 ka0[4], qa0[4]; float vv0, gg0, bb0;
    fl4 ka1[4], qa1[4]; float vv1, gg1, bb1;

    LOADSTEP(ka0, qa0, vv0, gg0, bb0, 0);
    for (int t = 0; t < T_LEN; t += 2) {
        LOADSTEP(ka1, qa1, vv1, gg1, bb1, t + 1);
        COMPUTE(ka0, qa0, vv0, gg0, bb0, t);
        const int t2 = (t + 2 < T_LEN) ? (t + 2) : (T_LEN - 1);
        LOADSTEP(ka0, qa0, vv0, gg0, bb0, t2);
        COMPUTE(ka1, qa1, vv1, gg1, bb1, t + 1);
    }
}

// ---------------------------------------------------------------------------
extern "C" void kernel_launch(void* const* d_in, const int* in_sizes, int n_in,
                              void* d_out, int out_size, void* d_ws, size_t ws_size,
                              hipStream_t stream)
{
    const float* x       = (const float*)d_in[0];
    const float* cs      = (const float*)d_in[1];
    const float* rs0     = (const float*)d_in[2];
    const float* b       = (const float*)d_in[3];
    const float* a       = (const float*)d_in[4];
    const float* w       = (const float*)d_in[5];
    const float* A_log   = (const float*)d_in[6];
    const float* dt_bias = (const float*)d_in[7];
    float* out = (float*)d_out;

    float* ws = (float*)d_ws;
    size_t off = 0;
    float* qn  = ws + off; off += (size_t)T_LEN * KEY_DIM;
    float* kn  = ws + off; off += (size_t)T_LEN * KEY_DIM;
    float* vb  = ws + off; off += (size_t)T_LEN * VAL_DIM;
    float* g   = ws + off; off += (size_t)T_LEN * NVH;
    float* be  = ws + off; off += (size_t)T_LEN * NVH;
    float* gam = ws + off; off += (size_t)NCHUNK * NVH * 64;
    float* bg  = ws + off; off += (size_t)NCHUNK * NVH * 64;
    float* KT  = ws + off; off += (size_t)NCHUNK * NKH * 64 * 64;
    float* QT  = ws + off; off += (size_t)NCHUNK * NKH * 64 * 64;
    float* MTt = ws + off; off += (size_t)NCHUNK * NVH * 64 * 64;
    float* SUt = ws + off; off += (size_t)NCHUNK * NVH * 64 * 64;
    const size_t need = off * sizeof(float);

    prep_kernel<<<T_LEN, 256, 0, stream>>>(x, cs, w, b, a, A_log, dt_bias,
                                           qn, kn, vb, g, be);
    if (ws_size >= need) {
        phase1_kernel<<<NCHUNK * NKH, 256, 0, stream>>>(qn, kn, g, be,
                                                        gam, bg, KT, QT, MTt, SUt);
        phase2_kernel<<<NVH * 8, 512, 0, stream>>>(vb, gam, bg, KT, QT, MTt, SUt,
                                                   rs0, out);
    } else {
        scan_kernel<<<NVH, 256, 0, stream>>>(qn, kn, vb, g, be, rs0, out);
    }
}